// Round 3
// baseline (686.444 us; speedup 1.0000x reference)
//
#include <hip/hip_runtime.h>
#include <math.h>

#define NB_ 3
#define B_ 4
#define N_ 1024
#define CQ_ 128
#define CKV_ 64
#define CP_ 16
#define H_ 4
#define D_ 32
#define R_ (B_*N_)
#define KW_ 128

__device__ __forceinline__ float sigmoidf_(float x) {
    return 1.0f / (1.0f + __expf(-x));
}

// LDS layout for pre/cp kernels (floats):
//   AN 8x132 | SA 8x68 | ST 8x68 | CR 8x68 | TH 8x132 | SCR 6x8x132
//   (SCR region aliased: ogs 8x132 + bms 8x260 during k_cp phase C,
//    and bm accumulators 2x8x260 during phase 4)
#define AN_OFF 0
#define SA_OFF 1056
#define ST_OFF 1600
#define CR_OFF 2144
#define TH_OFF 2688
#define SCR_OFF 3744
#define SMEM_F (3744 + 6336)

// ---------------------------------------------------------------------------
// pre_body: LN(a)+LN(c) -> AdaLN (attn & trans) -> qkvg proj -> silu-mul bm.
// Called with av = this thread's two elements of row (base + t/64),
// cols (t&63)*2 .. +1.  512 threads, 8 rows per block.
// ---------------------------------------------------------------------------
__device__ __forceinline__ void pre_body(
    float2 av, float* smem, int base,
    const float* __restrict__ c,
    const float* __restrict__ a_sg, const float* __restrict__ a_gw,
    const float* __restrict__ a_sw, const float* __restrict__ a_wso,
    const float* __restrict__ a_bso,
    const float* __restrict__ t_sg, const float* __restrict__ t_gw,
    const float* __restrict__ t_sw, const float* __restrict__ t_wso,
    const float* __restrict__ t_bso,
    const float* __restrict__ wq, const float* __restrict__ bq,
    const float* __restrict__ wk, const float* __restrict__ wv,
    const float* __restrict__ wg,
    const float* __restrict__ w1, const float* __restrict__ w2,
    float* __restrict__ qh, float* __restrict__ kh,
    float* __restrict__ vh, float* __restrict__ gh,
    float* __restrict__ bm,
    float* __restrict__ asig, float* __restrict__ tsig)
{
    const int t = threadIdx.x;
    // ---- phase 1: LN stats, one wave per row ----
    {
        const int rloc = t >> 6, li = t & 63;
        const int row = base + rloc;
        float s = av.x + av.y;
        float ss = av.x * av.x + av.y * av.y;
        float cv = c[row * 64 + li];
        float cs = cv, css = cv * cv;
        #pragma unroll
        for (int m = 1; m < 64; m <<= 1) {
            s += __shfl_xor(s, m);
            ss += __shfl_xor(ss, m);
            cs += __shfl_xor(cs, m);
            css += __shfl_xor(css, m);
        }
        const float am = s * (1.0f / 128.0f);
        const float ars = rsqrtf(ss * (1.0f / 128.0f) - am * am + 1e-5f);
        const float cm = cs * (1.0f / 64.0f);
        const float crs = rsqrtf(css * (1.0f / 64.0f) - cm * cm + 1e-5f);
        smem[AN_OFF + rloc * 132 + li * 2]     = (av.x - am) * ars;
        smem[AN_OFF + rloc * 132 + li * 2 + 1] = (av.y - am) * ars;
        const float cn = (cv - cm) * crs;
        smem[SA_OFF + rloc * 68 + li] = cn * a_sg[li];
        smem[ST_OFF + rloc * 68 + li] = cn * t_sg[li];
        smem[CR_OFF + rloc * 68 + li] = cv;
    }
    __syncthreads();

    const int wave = t >> 6;
    const int lane = t & 63;
    const int ig = lane >> 4;
    const int jc = lane & 15;
    const int c0 = jc * 8;
    const int r0 = ig * 2, r1 = ig * 2 + 1;

    // ---- phase 2: six K=64 GEMVs, one matrix per wave (waves 0..5) ----
    if (wave < 6) {
        const float* W;
        const float* xs;
        switch (wave) {
            case 0: W = a_gw;  xs = smem + SA_OFF; break;
            case 1: W = a_sw;  xs = smem + SA_OFF; break;
            case 2: W = t_gw;  xs = smem + ST_OFF; break;
            case 3: W = t_sw;  xs = smem + ST_OFF; break;
            case 4: W = a_wso; xs = smem + CR_OFF; break;
            default: W = t_wso; xs = smem + CR_OFF; break;
        }
        W += c0;
        float acc0[8], acc1[8];
        #pragma unroll
        for (int e = 0; e < 8; e++) { acc0[e] = 0.f; acc1[e] = 0.f; }
        for (int kk = 0; kk < 64; kk += 4) {
            float4 x40 = *(const float4*)(xs + r0 * 68 + kk);
            float4 x41 = *(const float4*)(xs + r1 * 68 + kk);
            #pragma unroll
            for (int qq = 0; qq < 4; qq++) {
                const float4 wlo = *(const float4*)(W + (kk + qq) * 128);
                const float4 whi = *(const float4*)(W + (kk + qq) * 128 + 4);
                const float xa = ((const float*)&x40)[qq];
                const float xb = ((const float*)&x41)[qq];
                acc0[0] += xa * wlo.x; acc0[1] += xa * wlo.y;
                acc0[2] += xa * wlo.z; acc0[3] += xa * wlo.w;
                acc0[4] += xa * whi.x; acc0[5] += xa * whi.y;
                acc0[6] += xa * whi.z; acc0[7] += xa * whi.w;
                acc1[0] += xb * wlo.x; acc1[1] += xb * wlo.y;
                acc1[2] += xb * wlo.z; acc1[3] += xb * wlo.w;
                acc1[4] += xb * whi.x; acc1[5] += xb * whi.y;
                acc1[6] += xb * whi.z; acc1[7] += xb * whi.w;
            }
        }
        float* sc = smem + SCR_OFF + wave * 1056;
        *(float4*)(sc + r0 * 132 + c0)     = make_float4(acc0[0], acc0[1], acc0[2], acc0[3]);
        *(float4*)(sc + r0 * 132 + c0 + 4) = make_float4(acc0[4], acc0[5], acc0[6], acc0[7]);
        *(float4*)(sc + r1 * 132 + c0)     = make_float4(acc1[0], acc1[1], acc1[2], acc1[3]);
        *(float4*)(sc + r1 * 132 + c0 + 4) = make_float4(acc1[4], acc1[5], acc1[6], acc1[7]);
    }
    __syncthreads();

    // ---- phase 3: combine -> ah (over AN), th, asig/tsig ----
    #pragma unroll
    for (int i2 = 0; i2 < 2; i2++) {
        const int e = t + i2 * 512;
        const int r = e >> 7, cc = e & 127;
        const float* sc = smem + SCR_OFF + r * 132 + cc;
        const float anv = smem[AN_OFF + r * 132 + cc];
        const float ahv = sigmoidf_(sc[0]) * anv + sc[1056];
        const float thv = sigmoidf_(sc[2 * 1056]) * anv + sc[3 * 1056];
        smem[AN_OFF + r * 132 + cc] = ahv;
        smem[TH_OFF + r * 132 + cc] = thv;
        const int idx = (base + r) * 128 + cc;
        asig[idx] = sigmoidf_(sc[4 * 1056] + a_bso[cc]);
        tsig[idx] = sigmoidf_(sc[5 * 1056] + t_bso[cc]);
    }
    __syncthreads();

    // ---- phase 4: K=128 GEMMs ----
    {
        const float* W;
        const float* xs;
        int ldw, sel2 = 0, cb = 0;
        if (wave < 4) {
            W = (wave == 0 ? wq : wave == 1 ? wk : wave == 2 ? wv : wg) + c0;
            xs = smem + AN_OFF;
            ldw = 128;
        } else {
            const int u = (wave - 4) * 128 + c0;
            sel2 = u >> 8; cb = u & 255;
            W = (sel2 ? w2 : w1) + cb;
            xs = smem + TH_OFF;
            ldw = 256;
        }
        float acc0[8], acc1[8];
        #pragma unroll
        for (int e = 0; e < 8; e++) {
            const float init = (wave == 0) ? bq[c0 + e] : 0.f;
            acc0[e] = init; acc1[e] = init;
        }
        for (int kk = 0; kk < 128; kk += 4) {
            float4 x40 = *(const float4*)(xs + r0 * 132 + kk);
            float4 x41 = *(const float4*)(xs + r1 * 132 + kk);
            #pragma unroll
            for (int qq = 0; qq < 4; qq++) {
                const float4 wlo = *(const float4*)(W + (kk + qq) * ldw);
                const float4 whi = *(const float4*)(W + (kk + qq) * ldw + 4);
                const float xa = ((const float*)&x40)[qq];
                const float xb = ((const float*)&x41)[qq];
                acc0[0] += xa * wlo.x; acc0[1] += xa * wlo.y;
                acc0[2] += xa * wlo.z; acc0[3] += xa * wlo.w;
                acc0[4] += xa * whi.x; acc0[5] += xa * whi.y;
                acc0[6] += xa * whi.z; acc0[7] += xa * whi.w;
                acc1[0] += xb * wlo.x; acc1[1] += xb * wlo.y;
                acc1[2] += xb * wlo.z; acc1[3] += xb * wlo.w;
                acc1[4] += xb * whi.x; acc1[5] += xb * whi.y;
                acc1[6] += xb * whi.z; acc1[7] += xb * whi.w;
            }
        }
        if (wave < 4) {
            float* dst = (wave == 0 ? qh : wave == 1 ? kh : wave == 2 ? vh : gh);
            if (wave == 3) {
                #pragma unroll
                for (int e = 0; e < 8; e++) {
                    acc0[e] = sigmoidf_(acc0[e]);
                    acc1[e] = sigmoidf_(acc1[e]);
                }
            }
            *(float4*)(dst + (base + r0) * 128 + c0)     = make_float4(acc0[0], acc0[1], acc0[2], acc0[3]);
            *(float4*)(dst + (base + r0) * 128 + c0 + 4) = make_float4(acc0[4], acc0[5], acc0[6], acc0[7]);
            *(float4*)(dst + (base + r1) * 128 + c0)     = make_float4(acc1[0], acc1[1], acc1[2], acc1[3]);
            *(float4*)(dst + (base + r1) * 128 + c0 + 4) = make_float4(acc1[4], acc1[5], acc1[6], acc1[7]);
        } else {
            float* bsc = smem + SCR_OFF + sel2 * 2080;
            *(float4*)(bsc + r0 * 260 + cb)     = make_float4(acc0[0], acc0[1], acc0[2], acc0[3]);
            *(float4*)(bsc + r0 * 260 + cb + 4) = make_float4(acc0[4], acc0[5], acc0[6], acc0[7]);
            *(float4*)(bsc + r1 * 260 + cb)     = make_float4(acc1[0], acc1[1], acc1[2], acc1[3]);
            *(float4*)(bsc + r1 * 260 + cb + 4) = make_float4(acc1[4], acc1[5], acc1[6], acc1[7]);
        }
    }
    __syncthreads();

    // ---- phase 4c: bm = silu(a1) * a2 ----
    #pragma unroll
    for (int i2 = 0; i2 < 4; i2++) {
        const int e = t + i2 * 512;
        const int r = e >> 8, cc = e & 255;
        const float a1 = smem[SCR_OFF + r * 260 + cc];
        const float a2 = smem[SCR_OFF + 2080 + r * 260 + cc];
        bm[(base + r) * 256 + cc] = a1 * sigmoidf_(a1) * a2;
    }
}

// ---------------------------------------------------------------------------
// k_pre0: zbias (all 3 blocks) + pre(block 0, a = q).  512 blocks x 512 thr.
// ---------------------------------------------------------------------------
__global__ __launch_bounds__(512, 4) void k_pre0(
    const float* __restrict__ a, const float* __restrict__ c,
    const float* __restrict__ p,
    const float* __restrict__ lnz_g, const float* __restrict__ lnz_b,
    const float* __restrict__ wb, float* __restrict__ zb,
    const float* __restrict__ a_sg, const float* __restrict__ a_gw,
    const float* __restrict__ a_sw, const float* __restrict__ a_wso,
    const float* __restrict__ a_bso,
    const float* __restrict__ t_sg, const float* __restrict__ t_gw,
    const float* __restrict__ t_sw, const float* __restrict__ t_wso,
    const float* __restrict__ t_bso,
    const float* __restrict__ wq, const float* __restrict__ bq,
    const float* __restrict__ wk, const float* __restrict__ wv,
    const float* __restrict__ wg,
    const float* __restrict__ w1, const float* __restrict__ w2,
    float* __restrict__ qh, float* __restrict__ kh,
    float* __restrict__ vh, float* __restrict__ gh,
    float* __restrict__ bm,
    float* __restrict__ asig, float* __restrict__ tsig)
{
    __shared__ float smem[SMEM_F];
    const int t = threadIdx.x;
    const int base = blockIdx.x * 8;

    // ---- zbias phase: 8 rows x 128 kk, 2 items per thread ----
    #pragma unroll
    for (int i = 0; i < 2; i++) {
        const int e = t + i * 512;
        const int r = e >> 7, kk = e & 127;
        const int row = base + r;
        const int n = row & 1023;
        const int k = ((n >> 5) << 5) - 48 + kk;
        if (k < 0 || k >= N_) {
            #pragma unroll
            for (int blk = 0; blk < NB_; blk++) {
                float* zo = zb + ((size_t)(blk * R_ + row) * H_) * KW_ + kk;
                #pragma unroll
                for (int h = 0; h < H_; h++) zo[h * KW_] = -1e10f;
            }
        } else {
            const float* pp = p + ((size_t)row * N_ + k) * CP_;
            float pv[16];
            float4 p0 = *(const float4*)(pp);
            float4 p1 = *(const float4*)(pp + 4);
            float4 p2 = *(const float4*)(pp + 8);
            float4 p3 = *(const float4*)(pp + 12);
            pv[0]=p0.x; pv[1]=p0.y; pv[2]=p0.z; pv[3]=p0.w;
            pv[4]=p1.x; pv[5]=p1.y; pv[6]=p1.z; pv[7]=p1.w;
            pv[8]=p2.x; pv[9]=p2.y; pv[10]=p2.z; pv[11]=p2.w;
            pv[12]=p3.x; pv[13]=p3.y; pv[14]=p3.z; pv[15]=p3.w;
            float s = 0.f, ss = 0.f;
            #pragma unroll
            for (int ii = 0; ii < 16; ii++) { s += pv[ii]; ss += pv[ii] * pv[ii]; }
            const float m = s * (1.0f / 16.0f);
            const float rs = rsqrtf(ss * (1.0f / 16.0f) - m * m + 1e-5f);
            #pragma unroll
            for (int blk = 0; blk < NB_; blk++) {
                const float* g = lnz_g + blk * 16;
                const float* bb = lnz_b + blk * 16;
                const float* w = wb + blk * 64;
                float z0 = 0.f, z1 = 0.f, z2 = 0.f, z3 = 0.f;
                #pragma unroll
                for (int cp = 0; cp < 16; cp++) {
                    const float val = (pv[cp] - m) * rs * g[cp] + bb[cp];
                    z0 += val * w[cp * 4 + 0];
                    z1 += val * w[cp * 4 + 1];
                    z2 += val * w[cp * 4 + 2];
                    z3 += val * w[cp * 4 + 3];
                }
                float* zo = zb + ((size_t)(blk * R_ + row) * H_) * KW_ + kk;
                zo[0] = z0; zo[KW_] = z1; zo[2 * KW_] = z2; zo[3 * KW_] = z3;
            }
        }
    }

    float2 av = *(const float2*)(a + (base + (t >> 6)) * 128 + (t & 63) * 2);
    pre_body(av, smem, base, c, a_sg, a_gw, a_sw, a_wso, a_bso,
             t_sg, t_gw, t_sw, t_wso, t_bso, wq, bq, wk, wv, wg, w1, w2,
             qh, kh, vh, gh, bm, asig, tsig);
}

// ---------------------------------------------------------------------------
// k_cp: combine(blk-1) [+ optional final store] + pre(blk).
// 512 blocks x 512 threads, 8 rows per block.
// ---------------------------------------------------------------------------
__global__ __launch_bounds__(512, 4) void k_cp(
    const float* __restrict__ og, const float* __restrict__ bm_in,
    const float* __restrict__ wo, const float* __restrict__ wout,
    const float* __restrict__ asig_in, const float* __restrict__ tsig_in,
    float* __restrict__ out_final, int final_,
    const float* __restrict__ c,
    const float* __restrict__ a_sg, const float* __restrict__ a_gw,
    const float* __restrict__ a_sw, const float* __restrict__ a_wso,
    const float* __restrict__ a_bso,
    const float* __restrict__ t_sg, const float* __restrict__ t_gw,
    const float* __restrict__ t_sw, const float* __restrict__ t_wso,
    const float* __restrict__ t_bso,
    const float* __restrict__ wq, const float* __restrict__ bq,
    const float* __restrict__ wk, const float* __restrict__ wv,
    const float* __restrict__ wg,
    const float* __restrict__ w1, const float* __restrict__ w2,
    float* __restrict__ qh, float* __restrict__ kh,
    float* __restrict__ vh, float* __restrict__ gh,
    float* __restrict__ bm,
    float* __restrict__ asig, float* __restrict__ tsig)
{
    __shared__ float smem[SMEM_F];
    float* ogs = smem + SCR_OFF;          // 8 x 132
    float* bms = smem + SCR_OFF + 1056;   // 8 x 260
    const int t = threadIdx.x;
    const int base = blockIdx.x * 8;

    // stage og (8x128) and bm (8x256) into LDS
    if (t < 256) {
        const int r = t >> 5, c4 = t & 31;
        *(float4*)(ogs + r * 132 + c4 * 4) =
            *(const float4*)(og + (base + r) * 128 + c4 * 4);
    }
    {
        const int r = t >> 6, c4 = t & 63;
        *(float4*)(bms + r * 260 + c4 * 4) =
            *(const float4*)(bm_in + (base + r) * 256 + c4 * 4);
    }
    __syncthreads();

    const int w = t >> 6, l = t & 63;
    const int row = base + w;
    float2 acc1 = make_float2(0.f, 0.f), acc2 = make_float2(0.f, 0.f);
    for (int k = 0; k < 128; k++) {
        const float x = ogs[w * 132 + k];
        const float2 wv = *(const float2*)(wo + k * 128 + l * 2);
        acc1.x += x * wv.x; acc1.y += x * wv.y;
    }
    for (int k = 0; k < 256; k++) {
        const float x = bms[w * 260 + k];
        const float2 wv = *(const float2*)(wout + k * 128 + l * 2);
        acc2.x += x * wv.x; acc2.y += x * wv.y;
    }
    const float2 as = *(const float2*)(asig_in + row * 128 + l * 2);
    const float2 ts = *(const float2*)(tsig_in + row * 128 + l * 2);
    float2 outv;
    outv.x = as.x * acc1.x + ts.x * acc2.x;
    outv.y = as.y * acc1.y + ts.y * acc2.y;

    if (final_) {
        *(float2*)(out_final + row * 128 + l * 2) = outv;
        return;
    }
    pre_body(outv, smem, base, c, a_sg, a_gw, a_sw, a_wso, a_bso,
             t_sg, t_gw, t_sw, t_wso, t_bso, wq, bq, wk, wv, wg, w1, w2,
             qh, kh, vh, gh, bm, asig, tsig);
}

// ---------------------------------------------------------------------------
// k_attn: local attention, 32 q x 128 k window, one tile per block.
// 512 blocks x 512 threads.
// ---------------------------------------------------------------------------
__global__ __launch_bounds__(512, 4) void k_attn(
    const float* __restrict__ qh, const float* __restrict__ kh,
    const float* __restrict__ vh, const float* __restrict__ gh,
    const float* __restrict__ zb, float* __restrict__ og)
{
    __shared__ float qs[32 * 36];
    __shared__ float kT[32 * 136];
    __shared__ float vs[128 * 36];
    __shared__ float wsm[32 * 132];

    const int t = threadIdx.x;
    const int qb = blockIdx.x & 31;
    const int h = (blockIdx.x >> 5) & 3;
    const int b = blockIdx.x >> 7;
    const int k0 = qb * 32 - 48;

    // stage K (transposed) and V
    #pragma unroll
    for (int i = 0; i < 2; i++) {
        const int e = t + i * 512;
        const int kk = e >> 3, dq = e & 7;
        const int kg = k0 + kk;
        float4 kv = make_float4(0.f, 0.f, 0.f, 0.f);
        float4 vv = make_float4(0.f, 0.f, 0.f, 0.f);
        if (kg >= 0 && kg < N_) {
            const int addr = (b * N_ + kg) * 128 + h * 32 + dq * 4;
            kv = *(const float4*)(kh + addr);
            vv = *(const float4*)(vh + addr);
        }
        kT[(dq * 4 + 0) * 136 + kk] = kv.x;
        kT[(dq * 4 + 1) * 136 + kk] = kv.y;
        kT[(dq * 4 + 2) * 136 + kk] = kv.z;
        kT[(dq * 4 + 3) * 136 + kk] = kv.w;
        *(float4*)(vs + kk * 36 + dq * 4) = vv;
    }
    // stage Q
    if (t < 256) {
        const int q = t >> 3, dq = t & 7;
        const int n = qb * 32 + q;
        *(float4*)(qs + q * 36 + dq * 4) =
            *(const float4*)(qh + (b * N_ + n) * 128 + h * 32 + dq * 4);
    }
    // per-thread bias slice
    const int q = t >> 4, jj = t & 15;
    const int n = qb * 32 + q;
    const float* zrow = zb + ((size_t)(b * N_ + n) * H_ + h) * KW_;
    const float4 z0 = *(const float4*)(zrow + jj * 8);
    const float4 z1 = *(const float4*)(zrow + jj * 8 + 4);
    __syncthreads();

    // QK^T: thread = (q, 8-key group)
    float acc[8];
    #pragma unroll
    for (int e = 0; e < 8; e++) acc[e] = 0.f;
    for (int d = 0; d < 32; d++) {
        const float qv = qs[q * 36 + d];
        const float4 ka = *(const float4*)(kT + d * 136 + jj * 8);
        const float4 kb = *(const float4*)(kT + d * 136 + jj * 8 + 4);
        acc[0] += qv * ka.x; acc[1] += qv * ka.y;
        acc[2] += qv * ka.z; acc[3] += qv * ka.w;
        acc[4] += qv * kb.x; acc[5] += qv * kb.y;
        acc[6] += qv * kb.z; acc[7] += qv * kb.w;
    }
    const float scale = 0.1767766952966369f;  // 1/sqrt(32)
    float fr[8];
    fr[0] = acc[0] * scale + z0.x; fr[1] = acc[1] * scale + z0.y;
    fr[2] = acc[2] * scale + z0.z; fr[3] = acc[3] * scale + z0.w;
    fr[4] = acc[4] * scale + z1.x; fr[5] = acc[5] * scale + z1.y;
    fr[6] = acc[6] * scale + z1.z; fr[7] = acc[7] * scale + z1.w;
    float mx = fr[0];
    #pragma unroll
    for (int i = 1; i < 8; i++) mx = fmaxf(mx, fr[i]);
    #pragma unroll
    for (int mk = 1; mk < 16; mk <<= 1) mx = fmaxf(mx, __shfl_xor(mx, mk));
    float sum = 0.f;
    #pragma unroll
    for (int i = 0; i < 8; i++) { fr[i] = __expf(fr[i] - mx); sum += fr[i]; }
    #pragma unroll
    for (int mk = 1; mk < 16; mk <<= 1) sum += __shfl_xor(sum, mk);
    const float rinv = 1.0f / sum;
    #pragma unroll
    for (int i = 0; i < 8; i++)
        wsm[q * 132 + jj * 8 + i] = fr[i] * rinv;
    __syncthreads();

    // P @ V: thread = (q, d-quad, k-half); pair-reduce over k-halves
    const int q2 = t >> 4, dq2 = (t >> 1) & 7, kh2 = t & 1;
    float4 o = make_float4(0.f, 0.f, 0.f, 0.f);
    const int kbeg = kh2 * 64;
    for (int kk = kbeg; kk < kbeg + 64; kk++) {
        const float wv = wsm[q2 * 132 + kk];
        const float4 v4 = *(const float4*)(vs + kk * 36 + dq2 * 4);
        o.x += wv * v4.x; o.y += wv * v4.y;
        o.z += wv * v4.z; o.w += wv * v4.w;
    }
    o.x += __shfl_xor(o.x, 1);
    o.y += __shfl_xor(o.y, 1);
    o.z += __shfl_xor(o.z, 1);
    o.w += __shfl_xor(o.w, 1);
    if (kh2 == 0) {
        const int n2 = qb * 32 + q2;
        const int addr = (b * N_ + n2) * 128 + h * 32 + dq2 * 4;
        const float4 g4 = *(const float4*)(gh + addr);
        float4 outv;
        outv.x = o.x * g4.x; outv.y = o.y * g4.y;
        outv.z = o.z * g4.z; outv.w = o.w * g4.w;
        *(float4*)(og + addr) = outv;
    }
}

// ---------------------------------------------------------------------------
extern "C" void kernel_launch(void* const* d_in, const int* in_sizes, int n_in,
                              void* d_out, int out_size, void* d_ws, size_t ws_size,
                              hipStream_t stream)
{
    const float* q        = (const float*)d_in[0];
    const float* c        = (const float*)d_in[1];
    const float* p        = (const float*)d_in[2];
    const float* a_sg_all = (const float*)d_in[3];
    const float* a_gw_all = (const float*)d_in[4];
    const float* a_sw_all = (const float*)d_in[5];
    const float* wq_all   = (const float*)d_in[6];
    const float* bq_all   = (const float*)d_in[7];
    const float* wk_all   = (const float*)d_in[8];
    const float* wv_all   = (const float*)d_in[9];
    const float* lnzg_all = (const float*)d_in[10];
    const float* lnzb_all = (const float*)d_in[11];
    const float* wb_all   = (const float*)d_in[12];
    const float* wgt_all  = (const float*)d_in[13];
    const float* wo_all   = (const float*)d_in[14];
    const float* awso_all = (const float*)d_in[15];
    const float* abso_all = (const float*)d_in[16];
    const float* t_sg_all = (const float*)d_in[17];
    const float* t_gw_all = (const float*)d_in[18];
    const float* t_sw_all = (const float*)d_in[19];
    const float* w1_all   = (const float*)d_in[20];
    const float* w2_all   = (const float*)d_in[21];
    const float* wout_all = (const float*)d_in[22];
    const float* twso_all = (const float*)d_in[23];
    const float* tbso_all = (const float*)d_in[24];

    float* ws = (float*)d_ws;
    const size_t RC = (size_t)R_ * CQ_;
    float* qh   = ws;
    float* kh   = ws + RC;
    float* vh   = ws + 2 * RC;
    float* gh   = ws + 3 * RC;
    float* bmb  = ws + 4 * RC;            // R*256
    float* asig = ws + 6 * RC;
    float* tsig = ws + 7 * RC;
    float* ogb  = ws + 8 * RC;
    float* zbb  = ws + 9 * RC;            // NB*R*H*KW = 12*RC

    // launch 1: zbias (all blocks) + pre(block 0)
    k_pre0<<<dim3(R_ / 8), dim3(512), 0, stream>>>(
        q, c, p, lnzg_all, lnzb_all, wb_all, zbb,
        a_sg_all, a_gw_all, a_sw_all, awso_all, abso_all,
        t_sg_all, t_gw_all, t_sw_all, twso_all, tbso_all,
        wq_all, bq_all, wk_all, wv_all, wgt_all, w1_all, w2_all,
        qh, kh, vh, gh, bmb, asig, tsig);

    for (int blk = 0; blk < NB_; blk++) {
        k_attn<<<dim3(512), dim3(512), 0, stream>>>(
            qh, kh, vh, gh, zbb + (size_t)blk * R_ * H_ * KW_, ogb);
        const int nxt = blk + 1;
        const int fin = (nxt == NB_);
        const int wi = fin ? 0 : nxt;  // pre weights (unused when final)
        k_cp<<<dim3(R_ / 8), dim3(512), 0, stream>>>(
            ogb, bmb, wo_all + blk * CQ_ * CQ_, wout_all + blk * 2 * CQ_ * CQ_,
            asig, tsig, (float*)d_out, fin,
            c,
            a_sg_all + wi * CKV_, a_gw_all + wi * CKV_ * CQ_,
            a_sw_all + wi * CKV_ * CQ_, awso_all + wi * CKV_ * CQ_,
            abso_all + wi * CQ_,
            t_sg_all + wi * CKV_, t_gw_all + wi * CKV_ * CQ_,
            t_sw_all + wi * CKV_ * CQ_, twso_all + wi * CKV_ * CQ_,
            tbso_all + wi * CQ_,
            wq_all + wi * CQ_ * CQ_, bq_all + wi * CQ_,
            wk_all + wi * CQ_ * CQ_, wv_all + wi * CQ_ * CQ_,
            wgt_all + wi * CQ_ * CQ_,
            w1_all + wi * CQ_ * 2 * CQ_, w2_all + wi * CQ_ * 2 * CQ_,
            qh, kh, vh, gh, bmb, asig, tsig);
    }
}